// Round 16
// baseline (52.256 us; speedup 1.0000x reference)
//
#include <hip/hip_runtime.h>
#include <math.h>

// ParametricEQ: 5-section cascaded biquad over (32, 131072).
// 10-state linear recurrence z' = A z + b x (A block-lower-triangular).
// TWO nodes: setup + one fused main kernel (R5 publish/wait topology with
// SGPR-P matrices, LCH=32, registers carry xr/es across the rendezvous,
// direct float4 y stores).
//   K1 setup: RBJ coeffs (fp64) + P_m = A^(32*2^m) m=0..11; zero flags.
//   K2 main (512 blocks x 256 thr; thread = 32-sample chunk, block = 8192):
//     x->regs; zero-state cascade; in-wave KS (P0..P5, SGPR); es in regs;
//     wave totals -> LDS; thread0 combines via P6, publishes agg (release);
//     wave0 acquire-spins on 16 sibling flags, KS over 16 aggs (P8..P11)
//     -> block seed; per-thread F = A^(32*lw)*(A^(2048*w)*S + E_w) + es;
//     final cascade -> direct stores (one 128B line per thread).

#define NB 32
#define LCH 32
#define T_LEN 131072
#define CPB 256                 // chunks per block
#define SPB 16                  // blocks per batch
#define NPOW 12

__constant__ double c_lo[15] = {-12.0,   20.0, 0.1,
                                -12.0,   20.0, 0.1,
                                -12.0,  200.0, 0.1,
                                -12.0, 2000.0, 0.1,
                                -12.0, 4000.0, 0.1};
__constant__ double c_hi[15] = { 12.0,  2000.0, 10.0,
                                 12.0,   200.0, 10.0,
                                 12.0,  2000.0, 10.0,
                                 12.0, 12000.0, 10.0,
                                 12.0, 16000.0, 10.0};

// ---------------- K1: coeffs + cascade matrix powers + flag clear -----------
__global__ __launch_bounds__(128)
void eq_setup(const float* __restrict__ cp, float* __restrict__ sos_out,
              float* __restrict__ powers, unsigned int* __restrict__ flags)
{
    int b = blockIdx.x;
    int t = threadIdx.x;
    __shared__ float  sc[5][5];
    __shared__ double Abuf[2][10][10];

    if (t < SPB) flags[b * SPB + t] = 0u;   // re-arm publish flags each launch

    if (t < 5) {
        int k = t;
        double p[3];
#pragma unroll
        for (int j = 0; j < 3; ++j) {
            int i = k * 3 + j;
            double pv = (double)cp[b * 15 + i];
            p[j] = c_lo[i] + pv * (c_hi[i] - c_lo[i]);
        }
        double A     = exp(p[0] * (M_LN10 / 40.0));
        double w0    = 2.0 * M_PI * p[1] / 44100.0;
        double alpha = sin(w0) / (2.0 * p[2]);
        double cw    = cos(w0);
        double sA    = sqrt(A);
        double b0, b1, b2, a0, a1, a2;
        if (k == 0) {            // low shelf
            b0 =     A * ((A + 1) - (A - 1) * cw + 2 * sA * alpha);
            b1 = 2 * A * ((A - 1) - (A + 1) * cw);
            b2 =     A * ((A + 1) - (A - 1) * cw - 2 * sA * alpha);
            a0 =          (A + 1) + (A - 1) * cw + 2 * sA * alpha;
            a1 =    -2 * ((A - 1) + (A + 1) * cw);
            a2 =          (A + 1) + (A - 1) * cw - 2 * sA * alpha;
        } else if (k == 4) {     // high shelf
            b0 =     A * ((A + 1) + (A - 1) * cw + 2 * sA * alpha);
            b1 = -2 * A * ((A - 1) + (A + 1) * cw);
            b2 =     A * ((A + 1) + (A - 1) * cw - 2 * sA * alpha);
            a0 =          (A + 1) - (A - 1) * cw + 2 * sA * alpha;
            a1 =     2 * ((A - 1) - (A + 1) * cw);
            a2 =          (A + 1) - (A - 1) * cw - 2 * sA * alpha;
        } else {                 // peaking
            b0 = 1.0 + alpha * A;
            b1 = -2.0 * cw;
            b2 = 1.0 - alpha * A;
            a0 = 1.0 + alpha / A;
            a1 = -2.0 * cw;
            a2 = 1.0 - alpha / A;
        }
        double inv = 1.0 / a0;
        float fb0 = (float)(b0 * inv), fb1 = (float)(b1 * inv), fb2 = (float)(b2 * inv);
        float fa1 = (float)(a1 * inv), fa2 = (float)(a2 * inv);
        float* o = sos_out + (size_t)(b * 5 + k) * 6;
        o[0] = fb0; o[1] = fb1; o[2] = fb2; o[3] = 1.0f; o[4] = fa1; o[5] = fa2;
        sc[k][0] = fb0; sc[k][1] = fb1; sc[k][2] = fb2; sc[k][3] = fa1; sc[k][4] = fa2;
    }
    __syncthreads();

    // A (10x10): column i = one-sample cascade update of basis e_i with x=0.
    if (t < 10) {
        double z[10];
#pragma unroll
        for (int i = 0; i < 10; ++i) z[i] = 0.0;
        z[t] = 1.0;
        double s = 0.0;
        double zn[10];
#pragma unroll
        for (int k = 0; k < 5; ++k) {
            double b0 = sc[k][0], b1 = sc[k][1], b2 = sc[k][2];
            double a1 = sc[k][3], a2 = sc[k][4];
            double y = b0 * s + z[2 * k];
            zn[2 * k]     = b1 * s - a1 * y + z[2 * k + 1];
            zn[2 * k + 1] = b2 * s - a2 * y;
            s = y;
        }
#pragma unroll
        for (int r = 0; r < 10; ++r) Abuf[0][r][t] = zn[r];
    }
    __syncthreads();

    int r = t / 10, cc = t % 10;
    int cur = 0;
    for (int sq = 0; sq < 16; ++sq) {
        double acc = 0.0;
        if (t < 100) {
#pragma unroll
            for (int j = 0; j < 10; ++j) acc += Abuf[cur][r][j] * Abuf[cur][j][cc];
        }
        __syncthreads();
        if (t < 100) Abuf[cur ^ 1][r][cc] = acc;
        __syncthreads();
        cur ^= 1;
        if (sq >= 4 && t < 100) {
            int m = sq - 4;   // sq=4 -> A^32 = P_0 ... sq=15 -> A^65536 = P_11
            powers[((size_t)b * NPOW + m) * 100 + t] = (float)Abuf[cur][r][cc];
        }
    }
}

// ---- triangular affine: v = P*u (+v if ACC); P is a GLOBAL 10x10 matrix
// addressed wave-uniformly -> s_load / SGPR operands. Row rr uses cols
// 0..(rr|1) (block-lower-triangular, exact zeros). ----
template<bool ACC>
__device__ __forceinline__ void affineT(const float* __restrict__ P,
                                        const float u[10], float v[10])
{
#pragma unroll
    for (int rr = 0; rr < 10; ++rr) {
        const float* rp = P + rr * 10;
        float a = ACC ? v[rr] : 0.0f;
#pragma unroll
        for (int c = 0; c <= (rr | 1); ++c) a = fmaf(rp[c], u[c], a);
        v[rr] = a;
    }
}

__device__ __forceinline__ void matvecT(const float* __restrict__ P, float v[10])
{
    float u[10];
#pragma unroll
    for (int i = 0; i < 10; ++i) u[i] = v[i];
    affineT<false>(P, u, v);
}

// ---------------- K2: fused main ----------------
__global__ __launch_bounds__(256, 2)
void eq_main(const float* __restrict__ x, const float* __restrict__ sos,
             const float* __restrict__ powers, float* __restrict__ agg,
             unsigned int* __restrict__ flags, float* __restrict__ y)
{
    int blk = blockIdx.x;
    int b = blk >> 4, sp = blk & (SPB - 1);
    int tid = threadIdx.x;
    int w = tid >> 6, lw = tid & 63;

    __shared__ float wt[4][10];    // per-wave 2048-sample totals
    __shared__ float Sseed[10];    // block entering state (batch prefix)

    const float* Pb = powers + (size_t)b * NPOW * 100;

    const float* s5 = sos + (size_t)(b * 5) * 6;
    float cb0[5], cb1[5], cb2[5], ca1[5], ca2[5];
#pragma unroll
    for (int k = 0; k < 5; ++k) {
        cb0[k] = s5[k * 6 + 0]; cb1[k] = s5[k * 6 + 1]; cb2[k] = s5[k * 6 + 2];
        ca1[k] = s5[k * 6 + 4]; ca2[k] = s5[k * 6 + 5];
    }

    // ---- x -> registers (kept live across the rendezvous) ----
    int c = sp * CPB + tid;
    const float* xp = x + (size_t)b * T_LEN + (size_t)c * LCH;
    float xr[LCH];
#pragma unroll
    for (int t0 = 0; t0 < LCH; t0 += 4) {
        float4 xv = *reinterpret_cast<const float4*>(xp + t0);
        xr[t0] = xv.x; xr[t0 + 1] = xv.y; xr[t0 + 2] = xv.z; xr[t0 + 3] = xv.w;
    }

    // ---- zero-state cascade -> chunk end state ----
    float z1[5] = {0, 0, 0, 0, 0}, z2[5] = {0, 0, 0, 0, 0};
#pragma unroll
    for (int j = 0; j < LCH; ++j) {
        float s = xr[j];
#pragma unroll
        for (int k = 0; k < 5; ++k) {
            float yk = fmaf(cb0[k], s, z1[k]);
            float u  = fmaf(cb1[k], s, z2[k]);
            z1[k] = fmaf(-ca1[k], yk, u);
            z2[k] = fmaf(-ca2[k], yk, cb2[k] * s);
            s = yk;
        }
    }
    float sv[10];
#pragma unroll
    for (int k = 0; k < 5; ++k) { sv[2 * k] = z1[k]; sv[2 * k + 1] = z2[k]; }

    // ---- in-wave KS scan over 64 chunks (P_0..P_5, SGPR operands) ----
#pragma unroll
    for (int j = 0; j < 6; ++j) {
        const float* P = Pb + j * 100;
        float u[10];
#pragma unroll
        for (int i = 0; i < 10; ++i) u[i] = __shfl_up(sv[i], 1 << j);
        if (lw >= (1 << j)) affineT<true>(P, u, sv);
    }

    // exclusive in-wave prefix, kept in registers
    float es[10];
#pragma unroll
    for (int i = 0; i < 10; ++i) {
        float e = __shfl_up(sv[i], 1);
        es[i] = (lw == 0) ? 0.0f : e;
    }
    if (lw == 63) {
#pragma unroll
        for (int i = 0; i < 10; ++i) wt[w][i] = sv[i];
    }
    __syncthreads();

    // ---- thread 0: block aggregate E = P6*E + wt[j], publish (release) ----
    if (tid == 0) {
        float E[10];
#pragma unroll
        for (int i = 0; i < 10; ++i) E[i] = wt[0][i];
#pragma unroll
        for (int j = 1; j < 4; ++j) {
            matvecT(Pb + 6 * 100, E);
#pragma unroll
            for (int i = 0; i < 10; ++i) E[i] += wt[j][i];
        }
        float* ap = agg + (size_t)(b * SPB + sp) * 10;
#pragma unroll
        for (int i = 0; i < 10; ++i)
            __hip_atomic_store(&ap[i], E[i], __ATOMIC_RELAXED, __HIP_MEMORY_SCOPE_AGENT);
        __hip_atomic_store(&flags[b * SPB + sp], 1u, __ATOMIC_RELEASE,
                           __HIP_MEMORY_SCOPE_AGENT);
    }

    // ---- wave 0: wait 16 sibling aggregates, KS over 16 (P_8..P_11) ----
    if (w == 0) {
        float tv[10];
#pragma unroll
        for (int i = 0; i < 10; ++i) tv[i] = 0.0f;
        if (lw < SPB) {
            while (__hip_atomic_load(&flags[b * SPB + lw], __ATOMIC_ACQUIRE,
                                     __HIP_MEMORY_SCOPE_AGENT) == 0u) {
                __builtin_amdgcn_s_sleep(1);
            }
            const float* ap = agg + (size_t)(b * SPB + lw) * 10;
#pragma unroll
            for (int i = 0; i < 10; ++i)
                tv[i] = __hip_atomic_load(&ap[i], __ATOMIC_RELAXED,
                                          __HIP_MEMORY_SCOPE_AGENT);
        }
#pragma unroll
        for (int j = 0; j < 4; ++j) {
            const float* P = Pb + (8 + j) * 100;   // A^(8192*2^j)
            float u[10];
#pragma unroll
            for (int i = 0; i < 10; ++i) u[i] = __shfl_up(tv[i], 1 << j);
            if (lw >= (1 << j) && lw < SPB) affineT<true>(P, u, tv);
        }
        float sd[10];
#pragma unroll
        for (int i = 0; i < 10; ++i) sd[i] = __shfl(tv[i], (sp - 1) & 63);
        if (sp == 0) {
#pragma unroll
            for (int i = 0; i < 10; ++i) sd[i] = 0.0f;
        }
        if (lw == 0) {
#pragma unroll
            for (int i = 0; i < 10; ++i) Sseed[i] = sd[i];
        }
    }
    __syncthreads();

    // ---- F = A^(32*lw) * (A^(2048*w)*S + E_w) + es -> exact state ----
    float F[10];
#pragma unroll
    for (int i = 0; i < 10; ++i) F[i] = Sseed[i];
    if (w & 1) matvecT(Pb + 6 * 100, F);   // A^2048
    if (w & 2) matvecT(Pb + 7 * 100, F);   // A^4096
    {
        float Ew[10];
#pragma unroll
        for (int i = 0; i < 10; ++i) Ew[i] = 0.0f;
        for (int j = 0; j < w; ++j) {
            matvecT(Pb + 6 * 100, Ew);
#pragma unroll
            for (int i = 0; i < 10; ++i) Ew[i] += wt[j][i];
        }
#pragma unroll
        for (int i = 0; i < 10; ++i) F[i] += Ew[i];
    }
#pragma unroll
    for (int m = 0; m < 6; ++m) {
        if ((lw >> m) & 1) matvecT(Pb + m * 100, F);
    }
#pragma unroll
    for (int k = 0; k < 5; ++k) {
        z1[k] = F[2 * k]     + es[2 * k];
        z2[k] = F[2 * k + 1] + es[2 * k + 1];
    }

    // ---- final cascade -> direct y stores (one 128B line per thread) ----
    float* yp = y + (size_t)b * T_LEN + (size_t)c * LCH;
#pragma unroll
    for (int t0 = 0; t0 < LCH; t0 += 4) {
        float o4[4];
#pragma unroll
        for (int j = 0; j < 4; ++j) {
            float s = xr[t0 + j];
#pragma unroll
            for (int k = 0; k < 5; ++k) {
                float yk = fmaf(cb0[k], s, z1[k]);
                float u  = fmaf(cb1[k], s, z2[k]);
                z1[k] = fmaf(-ca1[k], yk, u);
                z2[k] = fmaf(-ca2[k], yk, cb2[k] * s);
                s = yk;
            }
            o4[j] = s;
        }
        *reinterpret_cast<float4*>(yp + t0) = make_float4(o4[0], o4[1], o4[2], o4[3]);
    }
}

extern "C" void kernel_launch(void* const* d_in, const int* in_sizes, int n_in,
                              void* d_out, int out_size, void* d_ws, size_t ws_size,
                              hipStream_t stream)
{
    const float* x  = (const float*)d_in[0];
    const float* cp = (const float*)d_in[1];
    float* out = (float*)d_out;
    float* sos = out + (size_t)NB * T_LEN;          // sos tail of d_out

    float*        powers = (float*)d_ws;                        // NB*NPOW*100
    float*        agg    = powers + (size_t)NB * NPOW * 100;    // NB*SPB*10
    unsigned int* flags  = (unsigned int*)(agg + (size_t)NB * SPB * 10);  // NB*SPB

    eq_setup<<<dim3(NB), dim3(128), 0, stream>>>(cp, sos, powers, flags);
    eq_main<<<dim3(NB * SPB), dim3(256), 0, stream>>>(x, sos, powers, agg, flags, out);
}

// Round 17
// 45.338 us; speedup vs baseline: 1.1526x; 1.1526x over previous
//
#include <hip/hip_runtime.h>
#include <math.h>

// ParametricEQ: 5-section cascaded biquad over (32, 131072).
// 10-state linear recurrence z' = A z + b x (A block-lower-triangular).
// Wait-free 3-kernel pipeline, LCH=64 geometry (scan overhead amortized 2x):
//   K1  setup : RBJ coeffs (fp64) + P_m = A^(64*2^m), m=0..10.
//   K2a pass1 : per 64-sample chunk zero-state cascade (x streamed in two
//               32-float register halves); in-wave KS (P0..P5); es -> global
//               (i-major, coalesced); lane63 -> wave total (32 per batch).
//   K2b pass2 : in-wave scan of 32 wave totals (P6..P10) -> seed (shfl);
//               F = A^(64*lw)*seed + es -> exact state; streamed final
//               cascade -> direct float4 stores (2 full lines per thread).
// P matrices via wave-uniform global loads (s_load / SGPR operands).

#define NB 32
#define LCH 64
#define T_LEN 131072
#define CPB 256                 // chunks per block
#define BPB 8                   // blocks per batch
#define CCH 2048                // chunks per batch
#define WPB 32                  // waves per batch
#define NPOW 11

__constant__ double c_lo[15] = {-12.0,   20.0, 0.1,
                                -12.0,   20.0, 0.1,
                                -12.0,  200.0, 0.1,
                                -12.0, 2000.0, 0.1,
                                -12.0, 4000.0, 0.1};
__constant__ double c_hi[15] = { 12.0,  2000.0, 10.0,
                                 12.0,   200.0, 10.0,
                                 12.0,  2000.0, 10.0,
                                 12.0, 12000.0, 10.0,
                                 12.0, 16000.0, 10.0};

// ---------------- K1: coeffs + cascade matrix powers -----------------------
__global__ __launch_bounds__(128)
void eq_setup(const float* __restrict__ cp, float* __restrict__ sos_out,
              float* __restrict__ powers)
{
    int b = blockIdx.x;
    int t = threadIdx.x;
    __shared__ float  sc[5][5];
    __shared__ double Abuf[2][10][10];

    if (t < 5) {
        int k = t;
        double p[3];
#pragma unroll
        for (int j = 0; j < 3; ++j) {
            int i = k * 3 + j;
            double pv = (double)cp[b * 15 + i];
            p[j] = c_lo[i] + pv * (c_hi[i] - c_lo[i]);
        }
        double A     = exp(p[0] * (M_LN10 / 40.0));
        double w0    = 2.0 * M_PI * p[1] / 44100.0;
        double alpha = sin(w0) / (2.0 * p[2]);
        double cw    = cos(w0);
        double sA    = sqrt(A);
        double b0, b1, b2, a0, a1, a2;
        if (k == 0) {            // low shelf
            b0 =     A * ((A + 1) - (A - 1) * cw + 2 * sA * alpha);
            b1 = 2 * A * ((A - 1) - (A + 1) * cw);
            b2 =     A * ((A + 1) - (A - 1) * cw - 2 * sA * alpha);
            a0 =          (A + 1) + (A - 1) * cw + 2 * sA * alpha;
            a1 =    -2 * ((A - 1) + (A + 1) * cw);
            a2 =          (A + 1) + (A - 1) * cw - 2 * sA * alpha;
        } else if (k == 4) {     // high shelf
            b0 =     A * ((A + 1) + (A - 1) * cw + 2 * sA * alpha);
            b1 = -2 * A * ((A - 1) + (A + 1) * cw);
            b2 =     A * ((A + 1) + (A - 1) * cw - 2 * sA * alpha);
            a0 =          (A + 1) - (A - 1) * cw + 2 * sA * alpha;
            a1 =     2 * ((A - 1) - (A + 1) * cw);
            a2 =          (A + 1) - (A - 1) * cw - 2 * sA * alpha;
        } else {                 // peaking
            b0 = 1.0 + alpha * A;
            b1 = -2.0 * cw;
            b2 = 1.0 - alpha * A;
            a0 = 1.0 + alpha / A;
            a1 = -2.0 * cw;
            a2 = 1.0 - alpha / A;
        }
        double inv = 1.0 / a0;
        float fb0 = (float)(b0 * inv), fb1 = (float)(b1 * inv), fb2 = (float)(b2 * inv);
        float fa1 = (float)(a1 * inv), fa2 = (float)(a2 * inv);
        float* o = sos_out + (size_t)(b * 5 + k) * 6;
        o[0] = fb0; o[1] = fb1; o[2] = fb2; o[3] = 1.0f; o[4] = fa1; o[5] = fa2;
        sc[k][0] = fb0; sc[k][1] = fb1; sc[k][2] = fb2; sc[k][3] = fa1; sc[k][4] = fa2;
    }
    __syncthreads();

    // A (10x10): column i = one-sample cascade update of basis e_i with x=0.
    if (t < 10) {
        double z[10];
#pragma unroll
        for (int i = 0; i < 10; ++i) z[i] = 0.0;
        z[t] = 1.0;
        double s = 0.0;
        double zn[10];
#pragma unroll
        for (int k = 0; k < 5; ++k) {
            double b0 = sc[k][0], b1 = sc[k][1], b2 = sc[k][2];
            double a1 = sc[k][3], a2 = sc[k][4];
            double y = b0 * s + z[2 * k];
            zn[2 * k]     = b1 * s - a1 * y + z[2 * k + 1];
            zn[2 * k + 1] = b2 * s - a2 * y;
            s = y;
        }
#pragma unroll
        for (int r = 0; r < 10; ++r) Abuf[0][r][t] = zn[r];
    }
    __syncthreads();

    int r = t / 10, cc = t % 10;
    int cur = 0;
    for (int sq = 0; sq < 16; ++sq) {
        double acc = 0.0;
        if (t < 100) {
#pragma unroll
            for (int j = 0; j < 10; ++j) acc += Abuf[cur][r][j] * Abuf[cur][j][cc];
        }
        __syncthreads();
        if (t < 100) Abuf[cur ^ 1][r][cc] = acc;
        __syncthreads();
        cur ^= 1;
        if (sq >= 5 && t < 100) {
            int m = sq - 5;   // sq=5 -> A^64 = P_0 ... sq=15 -> A^65536 = P_10
            powers[((size_t)b * NPOW + m) * 100 + t] = (float)Abuf[cur][r][cc];
        }
    }
}

// ---- triangular affine: v = P*u (+v if ACC); P is a GLOBAL 10x10 matrix
// addressed wave-uniformly -> s_load / SGPR operands. Row rr uses cols
// 0..(rr|1) (block-lower-triangular, exact zeros). ----
template<bool ACC>
__device__ __forceinline__ void affineT(const float* __restrict__ P,
                                        const float u[10], float v[10])
{
#pragma unroll
    for (int rr = 0; rr < 10; ++rr) {
        const float* rp = P + rr * 10;
        float a = ACC ? v[rr] : 0.0f;
#pragma unroll
        for (int c = 0; c <= (rr | 1); ++c) a = fmaf(rp[c], u[c], a);
        v[rr] = a;
    }
}

__device__ __forceinline__ void matvecT(const float* __restrict__ P, float v[10])
{
    float u[10];
#pragma unroll
    for (int i = 0; i < 10; ++i) u[i] = v[i];
    affineT<false>(P, u, v);
}

// ---------------- K2a: pass1 — per-chunk exclusive prefixes + wave totals ---
__global__ __launch_bounds__(256, 2)
void eq_pass1(const float* __restrict__ x, const float* __restrict__ sos,
              const float* __restrict__ powers, float* __restrict__ es_g,
              float* __restrict__ wt)
{
    int blk = blockIdx.x;
    int b = blk >> 3, sp = blk & (BPB - 1);
    int tid = threadIdx.x;
    int w = tid >> 6, lw = tid & 63;

    const float* s5 = sos + (size_t)(b * 5) * 6;
    float cb0[5], cb1[5], cb2[5], ca1[5], ca2[5];
#pragma unroll
    for (int k = 0; k < 5; ++k) {
        cb0[k] = s5[k * 6 + 0]; cb1[k] = s5[k * 6 + 1]; cb2[k] = s5[k * 6 + 2];
        ca1[k] = s5[k * 6 + 4]; ca2[k] = s5[k * 6 + 5];
    }

    int c = sp * CPB + tid;
    const float* xp = x + (size_t)b * T_LEN + (size_t)c * LCH;

    // zero-state cascade over 64 samples, x streamed in two 32-float halves
    float z1[5] = {0, 0, 0, 0, 0}, z2[5] = {0, 0, 0, 0, 0};
#pragma unroll
    for (int h = 0; h < 2; ++h) {
        float xr[32];
#pragma unroll
        for (int t0 = 0; t0 < 32; t0 += 4) {
            float4 xv = *reinterpret_cast<const float4*>(xp + h * 32 + t0);
            xr[t0] = xv.x; xr[t0 + 1] = xv.y; xr[t0 + 2] = xv.z; xr[t0 + 3] = xv.w;
        }
#pragma unroll
        for (int j = 0; j < 32; ++j) {
            float s = xr[j];
#pragma unroll
            for (int k = 0; k < 5; ++k) {
                float yk = fmaf(cb0[k], s, z1[k]);
                float u  = fmaf(cb1[k], s, z2[k]);
                z1[k] = fmaf(-ca1[k], yk, u);
                z2[k] = fmaf(-ca2[k], yk, cb2[k] * s);
                s = yk;
            }
        }
    }
    float sv[10];
#pragma unroll
    for (int k = 0; k < 5; ++k) { sv[2 * k] = z1[k]; sv[2 * k + 1] = z2[k]; }

    // in-wave KS scan over 64 chunks (P_0..P_5, SGPR operands)
    const float* Pb = powers + (size_t)b * NPOW * 100;
#pragma unroll
    for (int j = 0; j < 6; ++j) {
        const float* P = Pb + j * 100;
        float u[10];
#pragma unroll
        for (int i = 0; i < 10; ++i) u[i] = __shfl_up(sv[i], 1 << j);
        if (lw >= (1 << j)) affineT<true>(P, u, sv);
    }

    // exclusive in-wave prefix -> global (i-major, coalesced)
    float es[10];
#pragma unroll
    for (int i = 0; i < 10; ++i) es[i] = __shfl_up(sv[i], 1);
    if (lw == 0) {
#pragma unroll
        for (int i = 0; i < 10; ++i) es[i] = 0.0f;
    }
    float* ep = es_g + (size_t)b * 10 * CCH + c;
#pragma unroll
    for (int i = 0; i < 10; ++i) ep[(size_t)i * CCH] = es[i];

    if (lw == 63) {
        int wid = sp * 4 + w;
        float* wp = wt + (size_t)(b * WPB + wid) * 10;
#pragma unroll
        for (int i = 0; i < 10; ++i) wp[i] = sv[i];
    }
}

// ---------------- K2b: pass2 — fused scan + exact states + output ----------
__global__ __launch_bounds__(256, 2)
void eq_pass2(const float* __restrict__ x, const float* __restrict__ sos,
              const float* __restrict__ powers, const float* __restrict__ wt,
              const float* __restrict__ es_g, float* __restrict__ y)
{
    int blk = blockIdx.x;
    int b = blk >> 3, sp = blk & (BPB - 1);
    int tid = threadIdx.x;
    int w = tid >> 6, lw = tid & 63;

    const float* Pb = powers + (size_t)b * NPOW * 100;
    int wid = sp * 4 + w;                   // this wave's index in [0, 32)

    // ---- in-wave scan over this batch's 32 wave totals ----
    const float* wp = wt + (size_t)(b * WPB + (lw < WPB ? lw : WPB - 1)) * 10;
    float tau[10];
#pragma unroll
    for (int i = 0; i < 10; ++i) tau[i] = wp[i];

#pragma unroll
    for (int j = 0; j < 5; ++j) {           // KS over 32, distance 1<<j uses P_(6+j)
        const float* P = Pb + (6 + j) * 100;
        float u[10];
#pragma unroll
        for (int i = 0; i < 10; ++i) u[i] = __shfl_up(tau[i], 1 << j);
        if (lw >= (1 << j)) affineT<true>(P, u, tau);
    }

    // exclusive prefix; this wave's seed = lane (wid-1)'s inclusive (0 if wid==0)
    float F[10];
#pragma unroll
    for (int i = 0; i < 10; ++i) {
        float iv = __shfl(tau[i], (wid - 1) & 63);
        F[i] = (wid == 0) ? 0.0f : iv;
    }

    // ---- F = A^(64*lw) * seed (powers commute) ----
#pragma unroll
    for (int m = 0; m < 6; ++m) {
        if ((lw >> m) & 1) matvecT(Pb + m * 100, F);
    }

    const float* s5 = sos + (size_t)(b * 5) * 6;
    float cb0[5], cb1[5], cb2[5], ca1[5], ca2[5];
#pragma unroll
    for (int k = 0; k < 5; ++k) {
        cb0[k] = s5[k * 6 + 0]; cb1[k] = s5[k * 6 + 1]; cb2[k] = s5[k * 6 + 2];
        ca1[k] = s5[k * 6 + 4]; ca2[k] = s5[k * 6 + 5];
    }

    int c = sp * CPB + tid;
    const float* ep = es_g + (size_t)b * 10 * CCH + c;
    float z1[5], z2[5];
#pragma unroll
    for (int k = 0; k < 5; ++k) {
        z1[k] = F[2 * k]     + ep[(size_t)(2 * k) * CCH];
        z2[k] = F[2 * k + 1] + ep[(size_t)(2 * k + 1) * CCH];
    }

    // ---- final cascade, streamed in two halves -> direct float4 stores ----
    const float* xp = x + (size_t)b * T_LEN + (size_t)c * LCH;
    float* yp = y + (size_t)b * T_LEN + (size_t)c * LCH;
#pragma unroll
    for (int h = 0; h < 2; ++h) {
        float xr[32];
#pragma unroll
        for (int t0 = 0; t0 < 32; t0 += 4) {
            float4 xv = *reinterpret_cast<const float4*>(xp + h * 32 + t0);
            xr[t0] = xv.x; xr[t0 + 1] = xv.y; xr[t0 + 2] = xv.z; xr[t0 + 3] = xv.w;
        }
#pragma unroll
        for (int t0 = 0; t0 < 32; t0 += 4) {
            float o4[4];
#pragma unroll
            for (int j = 0; j < 4; ++j) {
                float s = xr[t0 + j];
#pragma unroll
                for (int k = 0; k < 5; ++k) {
                    float yk = fmaf(cb0[k], s, z1[k]);
                    float u  = fmaf(cb1[k], s, z2[k]);
                    z1[k] = fmaf(-ca1[k], yk, u);
                    z2[k] = fmaf(-ca2[k], yk, cb2[k] * s);
                    s = yk;
                }
                o4[j] = s;
            }
            *reinterpret_cast<float4*>(yp + h * 32 + t0) =
                make_float4(o4[0], o4[1], o4[2], o4[3]);
        }
    }
}

extern "C" void kernel_launch(void* const* d_in, const int* in_sizes, int n_in,
                              void* d_out, int out_size, void* d_ws, size_t ws_size,
                              hipStream_t stream)
{
    const float* x  = (const float*)d_in[0];
    const float* cp = (const float*)d_in[1];
    float* out = (float*)d_out;
    float* sos = out + (size_t)NB * T_LEN;          // sos tail of d_out

    float* powers = (float*)d_ws;                        // NB*NPOW*100
    float* wt     = powers + (size_t)NB * NPOW * 100;    // NB*WPB*10
    float* es_g   = wt + (size_t)NB * WPB * 10;          // NB*10*CCH

    eq_setup<<<dim3(NB), dim3(128), 0, stream>>>(cp, sos, powers);
    eq_pass1<<<dim3(NB * BPB), dim3(256), 0, stream>>>(x, sos, powers, es_g, wt);
    eq_pass2<<<dim3(NB * BPB), dim3(256), 0, stream>>>(x, sos, powers, wt, es_g, out);
}

// Round 18
// 44.463 us; speedup vs baseline: 1.1753x; 1.0197x over previous
//
#include <hip/hip_runtime.h>
#include <math.h>

// ParametricEQ: 5-section cascaded biquad over (32, 131072).
// 10-state linear recurrence z' = A z + b x (A block-lower-triangular).
// Wait-free 3-kernel pipeline, LCH=32 (bracketed optimum), SGPR-P matrices.
// R18: pass2 issues x/es loads BEFORE the wave-total scan (latency hidden
// under ~600 cyc of scan+reconstruct); setup uses 1 barrier per squaring.
//   K1  setup : RBJ coeffs (fp64) + P_m = A^(32*2^m), m=0..11.
//   K2a pass1 : per 32-sample chunk zero-state cascade; in-wave KS (P0..P5);
//               es -> global (i-major); lane63 -> wave total (64 per batch).
//   K2b pass2 : prefetch x+es; in-wave scan of 64 wave totals (P6..P11) ->
//               seed (shfl); F = A^(32*lw)*seed + es; final cascade ->
//               direct float4 stores (one 128B line per thread).

#define NB 32
#define LCH 32
#define T_LEN 131072
#define CPB 256                 // chunks per block
#define BPB 16                  // blocks per batch
#define CCH 4096                // chunks per batch
#define WPB 64                  // waves per batch
#define NPOW 12

__constant__ double c_lo[15] = {-12.0,   20.0, 0.1,
                                -12.0,   20.0, 0.1,
                                -12.0,  200.0, 0.1,
                                -12.0, 2000.0, 0.1,
                                -12.0, 4000.0, 0.1};
__constant__ double c_hi[15] = { 12.0,  2000.0, 10.0,
                                 12.0,   200.0, 10.0,
                                 12.0,  2000.0, 10.0,
                                 12.0, 12000.0, 10.0,
                                 12.0, 16000.0, 10.0};

// ---------------- K1: coeffs + cascade matrix powers -----------------------
__global__ __launch_bounds__(128)
void eq_setup(const float* __restrict__ cp, float* __restrict__ sos_out,
              float* __restrict__ powers)
{
    int b = blockIdx.x;
    int t = threadIdx.x;
    __shared__ float  sc[5][5];
    __shared__ double Abuf[2][10][10];

    if (t < 5) {
        int k = t;
        double p[3];
#pragma unroll
        for (int j = 0; j < 3; ++j) {
            int i = k * 3 + j;
            double pv = (double)cp[b * 15 + i];
            p[j] = c_lo[i] + pv * (c_hi[i] - c_lo[i]);
        }
        double A     = exp(p[0] * (M_LN10 / 40.0));
        double w0    = 2.0 * M_PI * p[1] / 44100.0;
        double alpha = sin(w0) / (2.0 * p[2]);
        double cw    = cos(w0);
        double sA    = sqrt(A);
        double b0, b1, b2, a0, a1, a2;
        if (k == 0) {            // low shelf
            b0 =     A * ((A + 1) - (A - 1) * cw + 2 * sA * alpha);
            b1 = 2 * A * ((A - 1) - (A + 1) * cw);
            b2 =     A * ((A + 1) - (A - 1) * cw - 2 * sA * alpha);
            a0 =          (A + 1) + (A - 1) * cw + 2 * sA * alpha;
            a1 =    -2 * ((A - 1) + (A + 1) * cw);
            a2 =          (A + 1) + (A - 1) * cw - 2 * sA * alpha;
        } else if (k == 4) {     // high shelf
            b0 =     A * ((A + 1) + (A - 1) * cw + 2 * sA * alpha);
            b1 = -2 * A * ((A - 1) + (A + 1) * cw);
            b2 =     A * ((A + 1) + (A - 1) * cw - 2 * sA * alpha);
            a0 =          (A + 1) - (A - 1) * cw + 2 * sA * alpha;
            a1 =     2 * ((A - 1) - (A + 1) * cw);
            a2 =          (A + 1) - (A - 1) * cw - 2 * sA * alpha;
        } else {                 // peaking
            b0 = 1.0 + alpha * A;
            b1 = -2.0 * cw;
            b2 = 1.0 - alpha * A;
            a0 = 1.0 + alpha / A;
            a1 = -2.0 * cw;
            a2 = 1.0 - alpha / A;
        }
        double inv = 1.0 / a0;
        float fb0 = (float)(b0 * inv), fb1 = (float)(b1 * inv), fb2 = (float)(b2 * inv);
        float fa1 = (float)(a1 * inv), fa2 = (float)(a2 * inv);
        float* o = sos_out + (size_t)(b * 5 + k) * 6;
        o[0] = fb0; o[1] = fb1; o[2] = fb2; o[3] = 1.0f; o[4] = fa1; o[5] = fa2;
        sc[k][0] = fb0; sc[k][1] = fb1; sc[k][2] = fb2; sc[k][3] = fa1; sc[k][4] = fa2;
    }
    __syncthreads();

    // A (10x10): column i = one-sample cascade update of basis e_i with x=0.
    if (t < 10) {
        double z[10];
#pragma unroll
        for (int i = 0; i < 10; ++i) z[i] = 0.0;
        z[t] = 1.0;
        double s = 0.0;
        double zn[10];
#pragma unroll
        for (int k = 0; k < 5; ++k) {
            double b0 = sc[k][0], b1 = sc[k][1], b2 = sc[k][2];
            double a1 = sc[k][3], a2 = sc[k][4];
            double y = b0 * s + z[2 * k];
            zn[2 * k]     = b1 * s - a1 * y + z[2 * k + 1];
            zn[2 * k + 1] = b2 * s - a2 * y;
            s = y;
        }
#pragma unroll
        for (int r = 0; r < 10; ++r) Abuf[0][r][t] = zn[r];
    }
    __syncthreads();

    int r = t / 10, cc = t % 10;
    int cur = 0;
    for (int sq = 0; sq < 16; ++sq) {
        // reads hit Abuf[cur]; writes go to Abuf[cur^1] -> no intra-step
        // hazard, single barrier per step (after the write) suffices.
        if (t < 100) {
            double acc = 0.0;
#pragma unroll
            for (int j = 0; j < 10; ++j) acc += Abuf[cur][r][j] * Abuf[cur][j][cc];
            Abuf[cur ^ 1][r][cc] = acc;
        }
        __syncthreads();
        cur ^= 1;
        if (sq >= 4 && t < 100) {
            int m = sq - 4;   // sq=4 -> A^32 = P_0 ... sq=15 -> A^65536 = P_11
            powers[((size_t)b * NPOW + m) * 100 + t] = (float)Abuf[cur][r][cc];
        }
    }
}

// ---- triangular affine: v = P*u (+v if ACC); P is a GLOBAL 10x10 matrix
// addressed wave-uniformly -> s_load / SGPR operands. Row rr uses cols
// 0..(rr|1) (block-lower-triangular, exact zeros). ----
template<bool ACC>
__device__ __forceinline__ void affineT(const float* __restrict__ P,
                                        const float u[10], float v[10])
{
#pragma unroll
    for (int rr = 0; rr < 10; ++rr) {
        const float* rp = P + rr * 10;
        float a = ACC ? v[rr] : 0.0f;
#pragma unroll
        for (int c = 0; c <= (rr | 1); ++c) a = fmaf(rp[c], u[c], a);
        v[rr] = a;
    }
}

__device__ __forceinline__ void matvecT(const float* __restrict__ P, float v[10])
{
    float u[10];
#pragma unroll
    for (int i = 0; i < 10; ++i) u[i] = v[i];
    affineT<false>(P, u, v);
}

// ---------------- K2a: pass1 — per-chunk exclusive prefixes + wave totals ---
__global__ __launch_bounds__(256, 2)
void eq_pass1(const float* __restrict__ x, const float* __restrict__ sos,
              const float* __restrict__ powers, float* __restrict__ es_g,
              float* __restrict__ wt)
{
    int blk = blockIdx.x;
    int b = blk >> 4, sp = blk & (BPB - 1);
    int tid = threadIdx.x;
    int w = tid >> 6, lw = tid & 63;

    // x loads issued first (latency hides under coeff s_loads + cascade head)
    int c = sp * CPB + tid;
    const float* xp = x + (size_t)b * T_LEN + (size_t)c * LCH;
    float xr[LCH];
#pragma unroll
    for (int t0 = 0; t0 < LCH; t0 += 4) {
        float4 xv = *reinterpret_cast<const float4*>(xp + t0);
        xr[t0] = xv.x; xr[t0 + 1] = xv.y; xr[t0 + 2] = xv.z; xr[t0 + 3] = xv.w;
    }

    const float* s5 = sos + (size_t)(b * 5) * 6;
    float cb0[5], cb1[5], cb2[5], ca1[5], ca2[5];
#pragma unroll
    for (int k = 0; k < 5; ++k) {
        cb0[k] = s5[k * 6 + 0]; cb1[k] = s5[k * 6 + 1]; cb2[k] = s5[k * 6 + 2];
        ca1[k] = s5[k * 6 + 4]; ca2[k] = s5[k * 6 + 5];
    }

    // zero-state cascade -> chunk end state
    float z1[5] = {0, 0, 0, 0, 0}, z2[5] = {0, 0, 0, 0, 0};
#pragma unroll
    for (int j = 0; j < LCH; ++j) {
        float s = xr[j];
#pragma unroll
        for (int k = 0; k < 5; ++k) {
            float yk = fmaf(cb0[k], s, z1[k]);
            float u  = fmaf(cb1[k], s, z2[k]);
            z1[k] = fmaf(-ca1[k], yk, u);
            z2[k] = fmaf(-ca2[k], yk, cb2[k] * s);
            s = yk;
        }
    }
    float sv[10];
#pragma unroll
    for (int k = 0; k < 5; ++k) { sv[2 * k] = z1[k]; sv[2 * k + 1] = z2[k]; }

    // in-wave KS scan over 64 chunks (P_0..P_5, SGPR operands)
    const float* Pb = powers + (size_t)b * NPOW * 100;
#pragma unroll
    for (int j = 0; j < 6; ++j) {
        const float* P = Pb + j * 100;
        float u[10];
#pragma unroll
        for (int i = 0; i < 10; ++i) u[i] = __shfl_up(sv[i], 1 << j);
        if (lw >= (1 << j)) affineT<true>(P, u, sv);
    }

    // exclusive in-wave prefix -> global (i-major, coalesced)
    float es[10];
#pragma unroll
    for (int i = 0; i < 10; ++i) es[i] = __shfl_up(sv[i], 1);
    if (lw == 0) {
#pragma unroll
        for (int i = 0; i < 10; ++i) es[i] = 0.0f;
    }
    float* ep = es_g + (size_t)b * 10 * CCH + c;
#pragma unroll
    for (int i = 0; i < 10; ++i) ep[(size_t)i * CCH] = es[i];

    if (lw == 63) {
        int wid = sp * 4 + w;
        float* wp = wt + (size_t)(b * WPB + wid) * 10;
#pragma unroll
        for (int i = 0; i < 10; ++i) wp[i] = sv[i];
    }
}

// ---------------- K2b: pass2 — fused scan + exact states + output ----------
__global__ __launch_bounds__(256, 2)
void eq_pass2(const float* __restrict__ x, const float* __restrict__ sos,
              const float* __restrict__ powers, const float* __restrict__ wt,
              const float* __restrict__ es_g, float* __restrict__ y)
{
    int blk = blockIdx.x;
    int b = blk >> 4, sp = blk & (BPB - 1);
    int tid = threadIdx.x;
    int w = tid >> 6, lw = tid & 63;

    const float* Pb = powers + (size_t)b * NPOW * 100;
    int wid = sp * 4 + w;                   // this wave's index in [0, 64)
    int c = sp * CPB + tid;

    // ---- prefetch: issue x and es loads FIRST; latency hides under scan ----
    const float* xp = x + (size_t)b * T_LEN + (size_t)c * LCH;
    float xr[LCH];
#pragma unroll
    for (int t2 = 0; t2 < LCH; t2 += 4) {
        float4 xv = *reinterpret_cast<const float4*>(xp + t2);
        xr[t2] = xv.x; xr[t2 + 1] = xv.y; xr[t2 + 2] = xv.z; xr[t2 + 3] = xv.w;
    }
    const float* ep = es_g + (size_t)b * 10 * CCH + c;
    float esv[10];
#pragma unroll
    for (int i = 0; i < 10; ++i) esv[i] = ep[(size_t)i * CCH];

    // ---- in-wave scan over this batch's 64 wave totals ----
    const float* wp = wt + (size_t)(b * WPB + lw) * 10;
    float tau[10];
#pragma unroll
    for (int i = 0; i < 10; ++i) tau[i] = wp[i];

#pragma unroll
    for (int j = 0; j < 6; ++j) {           // KS over 64, distance 1<<j uses P_(6+j)
        const float* P = Pb + (6 + j) * 100;
        float u[10];
#pragma unroll
        for (int i = 0; i < 10; ++i) u[i] = __shfl_up(tau[i], 1 << j);
        if (lw >= (1 << j)) affineT<true>(P, u, tau);
    }

    // exclusive prefix; this wave's seed = lane (wid-1)'s inclusive (0 if wid==0)
    float F[10];
#pragma unroll
    for (int i = 0; i < 10; ++i) {
        float iv = __shfl(tau[i], (wid - 1) & 63);
        F[i] = (wid == 0) ? 0.0f : iv;
    }

    // ---- F = A^(32*lw) * seed (powers commute) ----
#pragma unroll
    for (int m = 0; m < 6; ++m) {
        if ((lw >> m) & 1) matvecT(Pb + m * 100, F);
    }

    const float* s5 = sos + (size_t)(b * 5) * 6;
    float cb0[5], cb1[5], cb2[5], ca1[5], ca2[5];
#pragma unroll
    for (int k = 0; k < 5; ++k) {
        cb0[k] = s5[k * 6 + 0]; cb1[k] = s5[k * 6 + 1]; cb2[k] = s5[k * 6 + 2];
        ca1[k] = s5[k * 6 + 4]; ca2[k] = s5[k * 6 + 5];
    }

    float z1[5], z2[5];
#pragma unroll
    for (int k = 0; k < 5; ++k) {
        z1[k] = F[2 * k]     + esv[2 * k];
        z2[k] = F[2 * k + 1] + esv[2 * k + 1];
    }

    // ---- final cascade -> direct y stores (one 128B line per thread) ----
    float* yp = y + (size_t)b * T_LEN + (size_t)c * LCH;
#pragma unroll
    for (int t0 = 0; t0 < LCH; t0 += 4) {
        float o4[4];
#pragma unroll
        for (int j = 0; j < 4; ++j) {
            float s = xr[t0 + j];
#pragma unroll
            for (int k = 0; k < 5; ++k) {
                float yk = fmaf(cb0[k], s, z1[k]);
                float u  = fmaf(cb1[k], s, z2[k]);
                z1[k] = fmaf(-ca1[k], yk, u);
                z2[k] = fmaf(-ca2[k], yk, cb2[k] * s);
                s = yk;
            }
            o4[j] = s;
        }
        *reinterpret_cast<float4*>(yp + t0) = make_float4(o4[0], o4[1], o4[2], o4[3]);
    }
}

extern "C" void kernel_launch(void* const* d_in, const int* in_sizes, int n_in,
                              void* d_out, int out_size, void* d_ws, size_t ws_size,
                              hipStream_t stream)
{
    const float* x  = (const float*)d_in[0];
    const float* cp = (const float*)d_in[1];
    float* out = (float*)d_out;
    float* sos = out + (size_t)NB * T_LEN;          // sos tail of d_out

    float* powers = (float*)d_ws;                        // NB*NPOW*100
    float* wt     = powers + (size_t)NB * NPOW * 100;    // NB*WPB*10
    float* es_g   = wt + (size_t)NB * WPB * 10;          // NB*10*CCH

    eq_setup<<<dim3(NB), dim3(128), 0, stream>>>(cp, sos, powers);
    eq_pass1<<<dim3(NB * BPB), dim3(256), 0, stream>>>(x, sos, powers, es_g, wt);
    eq_pass2<<<dim3(NB * BPB), dim3(256), 0, stream>>>(x, sos, powers, wt, es_g, out);
}